// Round 1
// baseline (906.296 us; speedup 1.0000x reference)
//
#include <hip/hip_runtime.h>
#include <hip/hip_bf16.h>

#define NN 6607
#define HH 64
#define TT 3
#define EE 1000000

typedef __attribute__((ext_vector_type(8))) short bf16x8;
typedef __attribute__((ext_vector_type(4))) float f32x4;

// ---------------- CSR build ----------------

__global__ void hist_kernel(const int* __restrict__ ei, int* __restrict__ degI) {
    int e = blockIdx.x * 256 + threadIdx.x;
    int t = blockIdx.y;
    if (e >= EE) return;
    int dst = ei[t * 2 * EE + EE + e];
    atomicAdd(&degI[t * NN + dst], 1);
}

__global__ void scan_kernel(const int* __restrict__ degI, int* __restrict__ rowptr) {
    int t = blockIdx.x;
    __shared__ int sh[256];
    __shared__ int carry_sh;
    int tid = threadIdx.x;
    if (tid == 0) carry_sh = 0;
    __syncthreads();
    for (int base = 0; base < NN; base += 256) {
        int i = base + tid;
        int v = (i < NN) ? degI[t * NN + i] : 0;
        sh[tid] = v;
        __syncthreads();
        for (int off = 1; off < 256; off <<= 1) {
            int x = (tid >= off) ? sh[tid - off] : 0;
            __syncthreads();
            sh[tid] += x;
            __syncthreads();
        }
        int incl = sh[tid];
        int carry = carry_sh;
        if (i < NN) rowptr[t * (NN + 1) + i] = carry + incl - v;  // exclusive
        __syncthreads();
        if (tid == 255) carry_sh = carry + incl;
        __syncthreads();
    }
    if (tid == 0) rowptr[t * (NN + 1) + NN] = carry_sh;  // == EE
}

__global__ void fill_kernel(const int* __restrict__ ei, const int* __restrict__ rowptr,
                            int* __restrict__ cursor, int* __restrict__ csr) {
    int e = blockIdx.x * 256 + threadIdx.x;
    int t = blockIdx.y;
    if (e >= EE) return;
    int src = ei[t * 2 * EE + e];
    int dst = ei[t * 2 * EE + EE + e];
    int pos = atomicAdd(&cursor[t * NN + dst], 1);
    csr[t * EE + rowptr[t * (NN + 1) + dst] + pos] = src;
}

// ---------------- misc ----------------

__global__ void wconv_kernel(const float* __restrict__ w, __hip_bfloat16* __restrict__ wb, int n) {
    int i = blockIdx.x * 256 + threadIdx.x;
    if (i < n) wb[i] = __float2bfloat16(w[i]);
}

// ---------------- SAGE layer ----------------
// block = 256 threads = 4 waves, each wave owns one node; lane = channel.
// out[h] = relu( mean_k * Wl[h][k] + b[h] + x_i[k] * Wr[h][k] )

template <int LAYER>
__global__ void sage_kernel(const float* __restrict__ x_all,
                            const int* __restrict__ rowptr, const int* __restrict__ csr,
                            const float* __restrict__ W_l, const float* __restrict__ b_l,
                            const float* __restrict__ W_r,
                            float* __restrict__ y, __hip_bfloat16* __restrict__ yb) {
    int t = blockIdx.y;
    __shared__ float wlT[64][65];
    __shared__ float wrT[64][65];
    __shared__ float bias[64];
    const float* Wl = W_l + t * 64 * 64;
    const float* Wr = W_r + t * 64 * 64;
    for (int idx = threadIdx.x; idx < 4096; idx += 256) {
        int h = idx >> 6, k = idx & 63;
        wlT[k][h] = Wl[idx];
        wrT[k][h] = Wr[idx];
    }
    if (threadIdx.x < 64) bias[threadIdx.x] = b_l[t * 64 + threadIdx.x];
    __syncthreads();

    int lane = threadIdx.x & 63;
    int widx = threadIdx.x >> 6;
    int i = blockIdx.x * 4 + widx;
    if (i >= NN) return;

    const float* x = x_all + (LAYER == 2 ? (size_t)t * NN * HH : 0);
    int rp0 = rowptr[t * (NN + 1) + i];
    int rp1 = rowptr[t * (NN + 1) + i + 1];
    const int* cs = csr + t * EE;

    float a0 = 0.f, a1 = 0.f, a2 = 0.f, a3 = 0.f;
    int e = rp0;
    for (; e + 4 <= rp1; e += 4) {
        int s0 = cs[e], s1 = cs[e + 1], s2 = cs[e + 2], s3 = cs[e + 3];
        a0 += x[s0 * 64 + lane];
        a1 += x[s1 * 64 + lane];
        a2 += x[s2 * 64 + lane];
        a3 += x[s3 * 64 + lane];
    }
    for (; e < rp1; ++e) a0 += x[cs[e] * 64 + lane];
    float acc = (a0 + a1) + (a2 + a3);

    int d = rp1 - rp0;
    float mean = acc / (float)(d > 1 ? d : 1);
    float xi = x[i * 64 + lane];

    float out = bias[lane];
    for (int k = 0; k < 64; ++k) {
        float am = __shfl(mean, k, 64);
        float bm = __shfl(xi, k, 64);
        out += am * wlT[k][lane] + bm * wrT[k][lane];
    }
    out = fmaxf(out, 0.f);
    y[(size_t)t * NN * HH + i * 64 + lane] = out;
    if (LAYER == 2) yb[(size_t)t * NN * HH + i * 64 + lane] = __float2bfloat16(out);
}

// ---------------- reconstruction: recon[t] = h2[t] @ Wrec[t]^T + brec[t] ----------------
// One wave computes a 16-row x 256-col panel (16 j-tiles), A-frags held in regs.
// mfma_f32_16x16x32_bf16: A lane l holds A[l&15][(l>>4)*8 + 0..7]; C/D: col=lane&15, row=(lane>>4)*4+reg.

__global__ void recon_kernel(const short* __restrict__ h2b, const short* __restrict__ wrecb,
                             const float* __restrict__ brec, float* __restrict__ out) {
    constexpr int NI = (NN + 15) / 16;     // 413
    constexpr int NJC = (NN + 255) / 256;  // 26
    int lane = threadIdx.x & 63;
    int wid = blockIdx.x * 4 + (threadIdx.x >> 6);
    int total = NI * NJC * TT;
    if (wid >= total) return;
    int t = wid / (NI * NJC);
    int rem = wid % (NI * NJC);
    int jc = rem / NI;
    int it = rem % NI;
    int i0 = it * 16;

    int r = lane & 15;
    int kb = (lane >> 4) * 8;

    const short* A = h2b + (size_t)t * NN * HH;
    const short* B = wrecb + (size_t)t * NN * HH;

    bf16x8 a0 = *(const bf16x8*)(A + (i0 + r) * 64 + kb);
    bf16x8 a1 = *(const bf16x8*)(A + (i0 + r) * 64 + kb + 32);

    size_t obase = (size_t)t * NN * NN;
    int rbase = (lane >> 4) * 4;

    for (int jt = 0; jt < 16; ++jt) {
        int j0 = jc * 256 + jt * 16;
        if (j0 >= NN) break;
        bf16x8 b0 = *(const bf16x8*)(B + (j0 + r) * 64 + kb);
        bf16x8 b1 = *(const bf16x8*)(B + (j0 + r) * 64 + kb + 32);
        f32x4 acc = {0.f, 0.f, 0.f, 0.f};
        acc = __builtin_amdgcn_mfma_f32_16x16x32_bf16(a0, b0, acc, 0, 0, 0);
        acc = __builtin_amdgcn_mfma_f32_16x16x32_bf16(a1, b1, acc, 0, 0, 0);
        int col = j0 + r;
        if (col < NN) {
            float bb = brec[t * NN + col];
            #pragma unroll
            for (int q = 0; q < 4; ++q) {
                int row = i0 + rbase + q;
                if (row < NN) out[obase + (size_t)row * NN + col] = acc[q] + bb;
            }
        }
    }
}

// ---------------- launch ----------------

extern "C" void kernel_launch(void* const* d_in, const int* in_sizes, int n_in,
                              void* d_out, int out_size, void* d_ws, size_t ws_size,
                              hipStream_t stream) {
    const float* emb  = (const float*)d_in[0];
    const int*   ei   = (const int*)d_in[1];
    const float* W1l  = (const float*)d_in[2];
    const float* b1   = (const float*)d_in[3];
    const float* W1r  = (const float*)d_in[4];
    const float* W2l  = (const float*)d_in[5];
    const float* b2   = (const float*)d_in[6];
    const float* W2r  = (const float*)d_in[7];
    const float* Wrec = (const float*)d_in[8];
    const float* brec = (const float*)d_in[9];

    char* ws = (char*)d_ws;
    // offsets (bytes), all 16B aligned
    int*   degI   = (int*)(ws + 0);                       // 3*6607*4      = 79284 -> pad 79296
    int*   rowptr = (int*)(ws + 79296);                   // 3*6608*4      = 79296
    int*   cursor = (int*)(ws + 158592);                  // 79284 -> pad 79296
    int*   csr    = (int*)(ws + 237888);                  // 3e6*4         = 12000000
    float* h1     = (float*)(ws + 12237888);              // 3*6607*64*4   = 5074176
    short* h2b    = (short*)(ws + 17312064);              // (3*6607*64+4096)*2 = 2545280
    short* wrecb  = (short*)(ws + 19857344);              // 2545280  -> end 22402624

    float* o_emb   = (float*)d_out;                        // [T][N][H]
    float* o_recon = o_emb + (size_t)TT * NN * HH;         // [T][N][N]
    float* o_xinit = o_recon + (size_t)TT * NN * NN;       // [N][H]

    // zero degI + rowptr + cursor region
    hipMemsetAsync(d_ws, 0, 237888, stream);

    dim3 egrid((EE + 255) / 256, TT);
    hist_kernel<<<egrid, 256, 0, stream>>>(ei, degI);
    scan_kernel<<<TT, 256, 0, stream>>>(degI, rowptr);
    fill_kernel<<<egrid, 256, 0, stream>>>(ei, rowptr, cursor, csr);

    int nwr = TT * NN * HH;
    wconv_kernel<<<(nwr + 255) / 256, 256, 0, stream>>>(Wrec, (__hip_bfloat16*)wrecb, nwr);

    dim3 sgrid((NN + 3) / 4, TT);
    sage_kernel<1><<<sgrid, 256, 0, stream>>>(emb, rowptr, csr, W1l, b1, W1r, h1, nullptr);
    sage_kernel<2><<<sgrid, 256, 0, stream>>>(h1, rowptr, csr, W2l, b2, W2r, o_emb,
                                              (__hip_bfloat16*)h2b);

    constexpr int NI = (NN + 15) / 16;
    constexpr int NJC = (NN + 255) / 256;
    int total_waves = NI * NJC * TT;
    int rblocks = (total_waves + 3) / 4;
    recon_kernel<<<rblocks, 256, 0, stream>>>(h2b, wrecb, brec, o_recon);

    hipMemcpyAsync(o_xinit, emb, (size_t)NN * HH * sizeof(float),
                   hipMemcpyDeviceToDevice, stream);
}

// Round 2
// 758.306 us; speedup vs baseline: 1.1952x; 1.1952x over previous
//
#include <hip/hip_runtime.h>
#include <hip/hip_bf16.h>

#define NN 6607
#define HH 64
#define TT 3
#define EE 1000000

typedef __attribute__((ext_vector_type(8))) short bf16x8;
typedef __attribute__((ext_vector_type(4))) float f32x4;

// ---------------- CSR build ----------------

__global__ void hist_kernel(const int* __restrict__ ei, int* __restrict__ degI) {
    int e = blockIdx.x * 256 + threadIdx.x;
    int t = blockIdx.y;
    if (e >= EE) return;
    int dst = ei[t * 2 * EE + EE + e];
    atomicAdd(&degI[t * NN + dst], 1);
}

__global__ void scan_kernel(const int* __restrict__ degI, int* __restrict__ rowptr) {
    int t = blockIdx.x;
    __shared__ int sh[256];
    __shared__ int carry_sh;
    int tid = threadIdx.x;
    if (tid == 0) carry_sh = 0;
    __syncthreads();
    for (int base = 0; base < NN; base += 256) {
        int i = base + tid;
        int v = (i < NN) ? degI[t * NN + i] : 0;
        sh[tid] = v;
        __syncthreads();
        for (int off = 1; off < 256; off <<= 1) {
            int x = (tid >= off) ? sh[tid - off] : 0;
            __syncthreads();
            sh[tid] += x;
            __syncthreads();
        }
        int incl = sh[tid];
        int carry = carry_sh;
        if (i < NN) rowptr[t * (NN + 1) + i] = carry + incl - v;  // exclusive
        __syncthreads();
        if (tid == 255) carry_sh = carry + incl;
        __syncthreads();
    }
    if (tid == 0) rowptr[t * (NN + 1) + NN] = carry_sh;  // == EE
}

__global__ void fill_kernel(const int* __restrict__ ei, const int* __restrict__ rowptr,
                            int* __restrict__ cursor, int* __restrict__ csr) {
    int e = blockIdx.x * 256 + threadIdx.x;
    int t = blockIdx.y;
    if (e >= EE) return;
    int src = ei[t * 2 * EE + e];
    int dst = ei[t * 2 * EE + EE + e];
    int pos = atomicAdd(&cursor[t * NN + dst], 1);
    csr[t * EE + rowptr[t * (NN + 1) + dst] + pos] = src;
}

// ---------------- misc ----------------

__global__ void wconv_kernel(const float* __restrict__ w, __hip_bfloat16* __restrict__ wb, int n) {
    int i = blockIdx.x * 256 + threadIdx.x;
    if (i < n) wb[i] = __float2bfloat16(w[i]);
}

// ---------------- SAGE layer ----------------
// block = 256 threads = 4 waves, each wave owns one node; lane = channel.

template <int LAYER>
__global__ void sage_kernel(const float* __restrict__ x_all,
                            const int* __restrict__ rowptr, const int* __restrict__ csr,
                            const float* __restrict__ W_l, const float* __restrict__ b_l,
                            const float* __restrict__ W_r,
                            float* __restrict__ y, __hip_bfloat16* __restrict__ yb) {
    int t = blockIdx.y;
    __shared__ float wlT[64][65];
    __shared__ float wrT[64][65];
    __shared__ float bias[64];
    const float* Wl = W_l + t * 64 * 64;
    const float* Wr = W_r + t * 64 * 64;
    for (int idx = threadIdx.x; idx < 4096; idx += 256) {
        int h = idx >> 6, k = idx & 63;
        wlT[k][h] = Wl[idx];
        wrT[k][h] = Wr[idx];
    }
    if (threadIdx.x < 64) bias[threadIdx.x] = b_l[t * 64 + threadIdx.x];
    __syncthreads();

    int lane = threadIdx.x & 63;
    int widx = threadIdx.x >> 6;
    int i = blockIdx.x * 4 + widx;
    if (i >= NN) return;

    const float* x = x_all + (LAYER == 2 ? (size_t)t * NN * HH : 0);
    int rp0 = rowptr[t * (NN + 1) + i];
    int rp1 = rowptr[t * (NN + 1) + i + 1];
    const int* cs = csr + t * EE;

    float a0 = 0.f, a1 = 0.f, a2 = 0.f, a3 = 0.f;
    int e = rp0;
    for (; e + 4 <= rp1; e += 4) {
        int s0 = cs[e], s1 = cs[e + 1], s2 = cs[e + 2], s3 = cs[e + 3];
        a0 += x[s0 * 64 + lane];
        a1 += x[s1 * 64 + lane];
        a2 += x[s2 * 64 + lane];
        a3 += x[s3 * 64 + lane];
    }
    for (; e < rp1; ++e) a0 += x[cs[e] * 64 + lane];
    float acc = (a0 + a1) + (a2 + a3);

    int d = rp1 - rp0;
    float mean = acc / (float)(d > 1 ? d : 1);
    float xi = x[i * 64 + lane];

    float out = bias[lane];
    for (int k = 0; k < 64; ++k) {
        float am = __shfl(mean, k, 64);
        float bm = __shfl(xi, k, 64);
        out += am * wlT[k][lane] + bm * wrT[k][lane];
    }
    out = fmaxf(out, 0.f);
    y[(size_t)t * NN * HH + i * 64 + lane] = out;
    if (LAYER == 2) yb[(size_t)t * NN * HH + i * 64 + lane] = __float2bfloat16(out);
}

// ---------------- reconstruction: recon[t] = h2[t] @ Wrec[t]^T + brec[t] ----------------
// Block tile: 16 rows x 512 cols. 4 waves, wave w covers cols w*128..+127 (8 j-tiles).
// Results staged in LDS, then cooperatively written: per instruction, 2 rows x 2KB
// contiguous float4 stores -> full 64B-sector coverage (fixes 1.9x write amplification).

__global__ void recon_kernel(const short* __restrict__ h2b, const short* __restrict__ wrecb,
                             const float* __restrict__ brec, float* __restrict__ out) {
    constexpr int NI = (NN + 15) / 16;      // 413
    constexpr int NJC = (NN + 511) / 512;   // 13
    __shared__ float tile[16][512 + 4];     // +4 pad: MFMA-phase writes land 2-way (free)

    int bid = blockIdx.x;
    int t = bid / (NI * NJC);
    int rem = bid % (NI * NJC);
    int jc = rem / NI;
    int it = rem % NI;
    int i0 = it * 16;

    int lane = threadIdx.x & 63;
    int wid = threadIdx.x >> 6;
    int r = lane & 15;
    int kb = (lane >> 4) * 8;
    int rbase = (lane >> 4) * 4;

    const short* A = h2b + (size_t)t * NN * HH;
    const short* B = wrecb + (size_t)t * NN * HH;

    bf16x8 a0 = *(const bf16x8*)(A + (i0 + r) * 64 + kb);
    bf16x8 a1 = *(const bf16x8*)(A + (i0 + r) * 64 + kb + 32);

    #pragma unroll
    for (int jt = 0; jt < 8; ++jt) {
        int jloc = wid * 128 + jt * 16;
        int j0 = jc * 512 + jloc;          // max 6640+15=6655 < NN+64 (padded), safe
        bf16x8 b0 = *(const bf16x8*)(B + (j0 + r) * 64 + kb);
        bf16x8 b1 = *(const bf16x8*)(B + (j0 + r) * 64 + kb + 32);
        f32x4 acc = {0.f, 0.f, 0.f, 0.f};
        acc = __builtin_amdgcn_mfma_f32_16x16x32_bf16(a0, b0, acc, 0, 0, 0);
        acc = __builtin_amdgcn_mfma_f32_16x16x32_bf16(a1, b1, acc, 0, 0, 0);
        #pragma unroll
        for (int q = 0; q < 4; ++q) tile[rbase + q][jloc + r] = acc[q];
    }
    __syncthreads();

    // cooperative write: iteration k writes rows i0+2k (threads 0-127) and
    // i0+2k+1 (threads 128-255), each as 512 contiguous floats (float4/lane).
    int tid = threadIdx.x;
    int colloc = (tid & 127) << 2;   // 0..508
    int rhalf = tid >> 7;            // 0 or 1
    int colg = jc * 512 + colloc;
    if (colg >= NN) return;
    size_t obase = (size_t)t * NN * NN;
    bool full = (colg + 4 <= NN);

    const float* br = brec + t * NN;
    float bx = br[colg];
    float by = (colg + 1 < NN) ? br[colg + 1] : 0.f;
    float bz = (colg + 2 < NN) ? br[colg + 2] : 0.f;
    float bw = (colg + 3 < NN) ? br[colg + 3] : 0.f;

    for (int rr = rhalf; rr < 16; rr += 2) {
        int row = i0 + rr;
        if (row >= NN) break;
        f32x4 v = *(const f32x4*)&tile[rr][colloc];
        float* p = out + obase + (size_t)row * NN + colg;
        if (full) {
            f32x4 w = {v[0] + bx, v[1] + by, v[2] + bz, v[3] + bw};
            *(f32x4*)p = w;
        } else {
            p[0] = v[0] + bx;
            if (colg + 1 < NN) p[1] = v[1] + by;
            if (colg + 2 < NN) p[2] = v[2] + bz;
        }
    }
}

// ---------------- launch ----------------

extern "C" void kernel_launch(void* const* d_in, const int* in_sizes, int n_in,
                              void* d_out, int out_size, void* d_ws, size_t ws_size,
                              hipStream_t stream) {
    const float* emb  = (const float*)d_in[0];
    const int*   ei   = (const int*)d_in[1];
    const float* W1l  = (const float*)d_in[2];
    const float* b1   = (const float*)d_in[3];
    const float* W1r  = (const float*)d_in[4];
    const float* W2l  = (const float*)d_in[5];
    const float* b2   = (const float*)d_in[6];
    const float* W2r  = (const float*)d_in[7];
    const float* Wrec = (const float*)d_in[8];
    const float* brec = (const float*)d_in[9];

    char* ws = (char*)d_ws;
    int*   degI   = (int*)(ws + 0);                       // 79284 -> pad 79296
    int*   rowptr = (int*)(ws + 79296);                   // 79296
    int*   cursor = (int*)(ws + 158592);                  // 79284 -> pad 79296
    int*   csr    = (int*)(ws + 237888);                  // 12000000
    float* h1     = (float*)(ws + 12237888);              // 5074176
    short* h2b    = (short*)(ws + 17312064);              // (3*6607*64+4096)*2 = 2545280
    short* wrecb  = (short*)(ws + 19857344);              // 2545280 -> end 22402624

    float* o_emb   = (float*)d_out;                        // [T][N][H]
    float* o_recon = o_emb + (size_t)TT * NN * HH;         // [T][N][N]
    float* o_xinit = o_recon + (size_t)TT * NN * NN;       // [N][H]

    hipMemsetAsync(d_ws, 0, 237888, stream);

    dim3 egrid((EE + 255) / 256, TT);
    hist_kernel<<<egrid, 256, 0, stream>>>(ei, degI);
    scan_kernel<<<TT, 256, 0, stream>>>(degI, rowptr);
    fill_kernel<<<egrid, 256, 0, stream>>>(ei, rowptr, cursor, csr);

    int nwr = TT * NN * HH;
    wconv_kernel<<<(nwr + 255) / 256, 256, 0, stream>>>(Wrec, (__hip_bfloat16*)wrecb, nwr);

    dim3 sgrid((NN + 3) / 4, TT);
    sage_kernel<1><<<sgrid, 256, 0, stream>>>(emb, rowptr, csr, W1l, b1, W1r, h1, nullptr);
    sage_kernel<2><<<sgrid, 256, 0, stream>>>(h1, rowptr, csr, W2l, b2, W2r, o_emb,
                                              (__hip_bfloat16*)h2b);

    constexpr int NI = (NN + 15) / 16;
    constexpr int NJC = (NN + 511) / 512;
    int rblocks = NI * NJC * TT;
    recon_kernel<<<rblocks, 256, 0, stream>>>(h2b, wrecb, brec, o_recon);

    hipMemcpyAsync(o_xinit, emb, (size_t)NN * HH * sizeof(float),
                   hipMemcpyDeviceToDevice, stream);
}